// Round 17
// baseline (25.096 us; speedup 1.0000x reference)
//
#include <hip/hip_runtime.h>
#include <hip/hip_bf16.h>

#define NA 3
#define NT 32
#define NC 4
#define NR 8
#define NK 1024
#define NPIX 4096            // 64*64
#define NOUT (NT * NC * NK)  // 131072 complex outputs
#define NRK (NR * NK)        // 8192 (r,k) pairs

typedef __attribute__((ext_vector_type(8))) short bf16x8;
typedef __attribute__((ext_vector_type(4))) float f32x4;

static __device__ __forceinline__ short f2bf(float f) {
    union { __hip_bfloat16 h; short s; } u;
    u.h = __float2bfloat16(f);
    return u.s;
}

// ---------------------------------------------------------------------------
// nudft_mono: the ENTIRE pipeline in one launch.
//  - inline detect (r13-proven): block scans all 16K floats of candA;
//    any |v| > pi  =>  candA is mps (P(false-neg) ~ 2e-12).
//  - separable NUDFT (r11-r16-proven math): in-register Ex/Ey phasors,
//    A-fragments built in-register from x*mps (bitwise = old sp values),
//    2 MFMAs (K=64) per (ch, slice), f32 Ey-fold.
//  - fused combine epilogue, planar f32 out (r7-r16-proven).
// Block = 16 rk (r = bx>>6, k0 = (bx&63)*16), 512 thr = 8 waves:
//   wave w -> coil c = w&3, i-half = w>>2 (2 slices of 16 rows), a = 0..2.
// Lane rule: col = l&15 (rk and i-row), g = l>>4; A/B j-slots = g*8+e+32h
// (HW-permutation invariant, r11-proven); C row = g*4+reg (m89-verified).
// ---------------------------------------------------------------------------
__global__ __launch_bounds__(512, 4) void nudft_mono(
    const float* __restrict__ x,
    const float* __restrict__ candA,
    const float* __restrict__ candB,
    const float* __restrict__ phi,
    const float* __restrict__ dcf,
    const int*  __restrict__ sidx,
    float* __restrict__ out)
{
    __shared__ int sfl;
    __shared__ float2 ylds[2][12][16];

    // ---- inline detect ----
    if (threadIdx.x == 0) sfl = 0;
    __syncthreads();
    {
        const float4* A4 = (const float4*)candA;
        int loc = 0;
#pragma unroll
        for (int q = 0; q < 8; ++q) {
            const float4 v = A4[threadIdx.x + q * 512];
            if (fabsf(v.x) > 3.1416f || fabsf(v.y) > 3.1416f ||
                fabsf(v.z) > 3.1416f || fabsf(v.w) > 3.1416f) loc = 1;
        }
        if (loc) atomicOr(&sfl, 1);
    }
    __syncthreads();
    const float* __restrict__ trj = sfl ? candB : candA;
    const float* __restrict__ mps = sfl ? candA : candB;

    const int tid = threadIdx.x;
    const int w = tid >> 6, l = tid & 63, col = l & 15, g = l >> 4;
    const int c     = w & 3;        // coil (mps plane) for this wave
    const int ihalf = w >> 2;
    const int rk0 = blockIdx.x * 16;
    const int r = rk0 >> 10, k0 = rk0 & (NK - 1);
    const int k = k0 + col;

    const float t0 = trj[(r * 2 + 0) * NK + k];
    const float t1 = trj[(r * 2 + 1) * NK + k];

    // ---- Ex fragments in-register (r12-r16-proven) ----
    bf16x8 breh[2], bimh[2];
    {
        float pr[8], pi[8];
        float sr, cr; __sincosf(t1, &sr, &cr);
        float s0, c0; __sincosf(t1 * (float)(g * 8 - 32), &s0, &c0);
        pr[0] = c0; pi[0] = -s0;
#pragma unroll
        for (int e = 1; e < 8; ++e) {
            const float nr = pr[e-1] * cr + pi[e-1] * sr;
            const float ni = pi[e-1] * cr - pr[e-1] * sr;
            pr[e] = nr; pi[e] = ni;
        }
        union { bf16x8 v; short s[8]; } u0, u1;
#pragma unroll
        for (int e = 0; e < 8; ++e) { u0.s[e] = f2bf(pr[e]); u1.s[e] = f2bf(pi[e]); }
        breh[0] = u0.v; bimh[0] = u1.v;
        float s32, c32; __sincosf(32.f * t1, &s32, &c32);
#pragma unroll
        for (int e = 0; e < 8; ++e) {
            const float nr = pr[e] * c32 + pi[e] * s32;
            const float ni = pi[e] * c32 - pr[e] * s32;
            u0.s[e] = f2bf(nr); u1.s[e] = f2bf(ni);
        }
        breh[1] = u0.v; bimh[1] = u1.v;
    }

    // ---- Ey step rotation hoisted ----
    float syr, cyr; __sincosf(t0, &syr, &cyr);

    float yre[3] = {0.f, 0.f, 0.f}, yim[3] = {0.f, 0.f, 0.f};
#pragma unroll
    for (int sl = 0; sl < 2; ++sl) {
        const int i0 = ihalf * 32 + sl * 16;
        // Ey phasors: i = i0 + g*4 + reg (r12-r16-proven)
        float eyR[4], eyI[4];
        {
            float sb, cb; __sincosf(t0 * (float)(i0 + g * 4 - 32), &sb, &cb);
            eyR[0] = cb; eyI[0] = -sb;
#pragma unroll
            for (int q = 1; q < 4; ++q) {
                const float nr = eyR[q-1] * cyr + eyI[q-1] * syr;
                const float ni = eyI[q-1] * cyr - eyR[q-1] * syr;
                eyR[q] = nr; eyI[q] = ni;
            }
        }

        // pixel base for this lane: row = i0+col, j = g*8 (+32 for h=1)
        const int off = (i0 + col) * 64 + g * 8;
        // mps plane c, hoisted across the 3 a's
        const float4 mv00 = *(const float4*)&mps[c * NPIX + off];
        const float4 mv01 = *(const float4*)&mps[c * NPIX + off + 4];
        const float4 mv10 = *(const float4*)&mps[c * NPIX + off + 32];
        const float4 mv11 = *(const float4*)&mps[c * NPIX + off + 36];

#pragma unroll
        for (int a = 0; a < 3; ++a) {
            const float4 xv00 = *(const float4*)&x[a * NPIX + off];
            const float4 xv01 = *(const float4*)&x[a * NPIX + off + 4];
            const float4 xv10 = *(const float4*)&x[a * NPIX + off + 32];
            const float4 xv11 = *(const float4*)&x[a * NPIX + off + 36];
            union { bf16x8 v; short s[8]; } p0, p1;
            p0.s[0] = f2bf(xv00.x * mv00.x); p0.s[1] = f2bf(xv00.y * mv00.y);
            p0.s[2] = f2bf(xv00.z * mv00.z); p0.s[3] = f2bf(xv00.w * mv00.w);
            p0.s[4] = f2bf(xv01.x * mv01.x); p0.s[5] = f2bf(xv01.y * mv01.y);
            p0.s[6] = f2bf(xv01.z * mv01.z); p0.s[7] = f2bf(xv01.w * mv01.w);
            p1.s[0] = f2bf(xv10.x * mv10.x); p1.s[1] = f2bf(xv10.y * mv10.y);
            p1.s[2] = f2bf(xv10.z * mv10.z); p1.s[3] = f2bf(xv10.w * mv10.w);
            p1.s[4] = f2bf(xv11.x * mv11.x); p1.s[5] = f2bf(xv11.y * mv11.y);
            p1.s[6] = f2bf(xv11.z * mv11.z); p1.s[7] = f2bf(xv11.w * mv11.w);

            f32x4 gre = {0.f, 0.f, 0.f, 0.f}, gim = {0.f, 0.f, 0.f, 0.f};
            gre = __builtin_amdgcn_mfma_f32_16x16x32_bf16(p0.v, breh[0], gre, 0, 0, 0);
            gre = __builtin_amdgcn_mfma_f32_16x16x32_bf16(p1.v, breh[1], gre, 0, 0, 0);
            gim = __builtin_amdgcn_mfma_f32_16x16x32_bf16(p0.v, bimh[0], gim, 0, 0, 0);
            gim = __builtin_amdgcn_mfma_f32_16x16x32_bf16(p1.v, bimh[1], gim, 0, 0, 0);
#pragma unroll
            for (int reg = 0; reg < 4; ++reg) {
                yre[a] = fmaf(eyR[reg], gre[reg], fmaf(-eyI[reg], gim[reg], yre[a]));
                yim[a] = fmaf(eyR[reg], gim[reg], fmaf( eyI[reg], gre[reg], yim[a]));
            }
        }
    }

    // ---- reduce over g (lane bits 4,5), park partials in LDS ----
#pragma unroll
    for (int a = 0; a < 3; ++a) {
        float vr = yre[a], vi = yim[a];
        vr += __shfl_xor(vr, 16); vi += __shfl_xor(vi, 16);
        vr += __shfl_xor(vr, 32); vi += __shfl_xor(vi, 32);
        if (g == 0) ylds[ihalf][a * 4 + c][col] = make_float2(vr, vi);
    }
    __syncthreads();

    // ---- fused combine epilogue (r13-r16-proven; planar f32 out) ----
    bool is64 = true;
#pragma unroll
    for (int i = 1; i < 32; i += 2) is64 = is64 && (sidx[i] == 0);
#pragma unroll
    for (int q = 0; q < 4; ++q) {
        const int item = tid + q * 512;          // 32t x 4c x 16k = 2048
        const int kl = item & 15;
        const int cc = (item >> 4) & 3;
        const int t  = item >> 6;
        const int rt = is64 ? sidx[2 * t] : sidx[t];
        if (rt == r) {
            const float d = dcf[r * NK + k0 + kl];
            float ore = 0.f, oim = 0.f;
#pragma unroll
            for (int a = 0; a < NA; ++a) {
                const float p = phi[a * NT + t];
                const float2 v0 = ylds[0][a * 4 + cc][kl];
                const float2 v1 = ylds[1][a * 4 + cc][kl];
                ore = fmaf(p, v0.x + v1.x, ore);
                oim = fmaf(p, v0.y + v1.y, oim);
            }
            const int gid = t * 4096 + cc * 1024 + k0 + kl;
            out[gid]        = ore * d;
            out[NOUT + gid] = oim * d;
        }
    }
}

// ---------------------------------------------------------------------------
extern "C" void kernel_launch(void* const* d_in, const int* in_sizes, int n_in,
                              void* d_out, int out_size, void* d_ws, size_t ws_size,
                              hipStream_t stream) {
    // size-signature input resolution (robust to permutation; doc order default)
    int ix = 0, i16a = 1, iphi = 2, i16b = 3, idcf = 4, isidx = 5;
    int f16[2]; int n16 = 0, fx = -1, fphi = -1, fdcf = -1, fsidx = -1;
    for (int i = 0; i < n_in; ++i) {
        const int s = in_sizes[i];
        if (s == 12288) fx = i;
        else if (s == 96) fphi = i;
        else if (s == 8192) fdcf = i;
        else if (s == 16384) { if (n16 < 2) f16[n16] = i; ++n16; }
        else if (s == 32 || s == 64) fsidx = i;
    }
    if (fx >= 0 && fphi >= 0 && fdcf >= 0 && fsidx >= 0 && n16 == 2) {
        ix = fx; iphi = fphi; idcf = fdcf; isidx = fsidx;
        i16a = f16[0]; i16b = f16[1];
    }

    nudft_mono<<<NRK / 16, 512, 0, stream>>>(
        (const float*)d_in[ix], (const float*)d_in[i16a], (const float*)d_in[i16b],
        (const float*)d_in[iphi], (const float*)d_in[idcf], (const int*)d_in[isidx],
        (float*)d_out);
}